// Round 2
// baseline (1535.656 us; speedup 1.0000x reference)
//
#include <hip/hip_runtime.h>
#include <hip/hip_bf16.h>
#include <stdint.h>
#include <stddef.h>

#define NL 8
#define NH 12
#define CC 576
#define VV 16389
#define NB 2
#define TT 1024
#define HD 48
#define BT 2048
#define C3 1728
#define C2 1152

typedef __attribute__((ext_vector_type(4))) float f32x4;
typedef __attribute__((ext_vector_type(8))) __bf16 bf16x8;
typedef __attribute__((ext_vector_type(8))) unsigned short u16x8;

static __device__ __forceinline__ unsigned short f2bf(float f) {
  __hip_bfloat16 h = __float2bfloat16(f);
  return __builtin_bit_cast(unsigned short, h);
}

// ---------------- fp32 -> bf16 convert (weights) ----------------
__global__ void cvt_kernel(const float* __restrict__ in, unsigned short* __restrict__ out, int n4) {
  int i = blockIdx.x * blockDim.x + threadIdx.x;
  int stride = gridDim.x * blockDim.x;
  for (; i < n4; i += stride) {
    float4 v = reinterpret_cast<const float4*>(in)[i];
    ushort4 o;
    o.x = f2bf(v.x); o.y = f2bf(v.y); o.z = f2bf(v.z); o.w = f2bf(v.w);
    reinterpret_cast<ushort4*>(out)[i] = o;
  }
}

// ---------------- embedding gather ----------------
__global__ void embed_kernel(const int* __restrict__ idx, const float* __restrict__ wte,
                             float* __restrict__ x, float* __restrict__ x0,
                             unsigned short* __restrict__ xbf) {
  int t = blockIdx.x;
  int tok = idx[t];
  const float* src = wte + (size_t)tok * CC;
  size_t base = (size_t)t * CC;
  for (int c = threadIdx.x; c < CC; c += blockDim.x) {
    float v = src[c];
    x[base + c] = v;
    x0[base + c] = v;
    xbf[base + c] = f2bf(v);
  }
}

// ---------------- layernorm (+ optional lambda mix written back to x) ----------------
template<int MIX>
__global__ __launch_bounds__(256) void ln_kernel(
    const float* __restrict__ xin, const float* __restrict__ x0,
    const float* __restrict__ lam, const float* __restrict__ w,
    const float* __restrict__ b, float* __restrict__ xmix,
    unsigned short* __restrict__ hbf) {
  int row = blockIdx.x * 4 + (threadIdx.x >> 6);
  int lane = threadIdx.x & 63;
  size_t base = (size_t)row * CC;
  float lam0 = 1.f, lam1 = 0.f;
  if (MIX) { lam0 = lam[0]; lam1 = lam[1]; }
  float e[9];
  float s = 0.f;
#pragma unroll
  for (int j = 0; j < 9; ++j) {
    int c = lane + 64 * j;
    float v = xin[base + c];
    if (MIX) v = lam0 * v + lam1 * x0[base + c];
    e[j] = v; s += v;
  }
#pragma unroll
  for (int mm = 1; mm < 64; mm <<= 1) s += __shfl_xor(s, mm, 64);
  float mu = s * (1.f / 576.f);
  float var = 0.f;
#pragma unroll
  for (int j = 0; j < 9; ++j) { float d = e[j] - mu; var += d * d; }
#pragma unroll
  for (int mm = 1; mm < 64; mm <<= 1) var += __shfl_xor(var, mm, 64);
  float rstd = 1.f / sqrtf(var * (1.f / 576.f) + 1e-5f);
#pragma unroll
  for (int j = 0; j < 9; ++j) {
    int c = lane + 64 * j;
    if (MIX) xmix[base + c] = e[j];
    hbf[base + c] = f2bf((e[j] - mu) * rstd * w[c] + b[c]);
  }
}

// ---------------- v-residual mix: vb = bf16(0.5*v + 0.5*v1) ----------------
__global__ void vmix_kernel(const float* __restrict__ qkv, const float* __restrict__ v1,
                            unsigned short* __restrict__ vb) {
  int i = blockIdx.x * blockDim.x + threadIdx.x;
  const int n = BT * CC;
  int stride = gridDim.x * blockDim.x;
  for (; i < n; i += stride) {
    int row = i / CC, col = i - row * CC;
    vb[i] = f2bf(0.5f * qkv[(size_t)row * C3 + 2 * CC + col] + 0.5f * v1[i]);
  }
}

// ---------------- GEGLU: out = bf16(gelu_tanh(g) * u) ----------------
__global__ void geglu_kernel(const float* __restrict__ gf, const float* __restrict__ uf,
                             unsigned short* __restrict__ out) {
  int i = blockIdx.x * blockDim.x + threadIdx.x;
  const int n = BT * C2;
  int stride = gridDim.x * blockDim.x;
  for (; i < n; i += stride) {
    float gv = gf[i];
    float t = tanhf(0.7978845608028654f * (gv + 0.044715f * gv * gv * gv));
    out[i] = f2bf(0.5f * gv * (1.f + t) * uf[i]);
  }
}

// ---------------- bf16 MFMA GEMM: C[M,N] (+)= X[M,K] * W[N,K]^T ----------------
// EPI: 0 = store, 1 = accumulate into C (residual add), 2 = 30*tanh(v/30)
template<int EPI>
__global__ __launch_bounds__(256) void gemm_bt(
    const unsigned short* __restrict__ X, const unsigned short* __restrict__ W,
    float* __restrict__ Cmat, int M, int N, int K) {
  __shared__ unsigned short As[128 * 64];
  __shared__ unsigned short Bs[128 * 64];
  const int tid = threadIdx.x;
  const int lane = tid & 63;
  const int wv = tid >> 6;
  const int wr = wv >> 1, wc = wv & 1;
  const int m0 = blockIdx.y * 128, n0 = blockIdx.x * 128;
  const int l15 = lane & 15, g = lane >> 4;
  const int trow = tid >> 3;         // 0..31
  const int tcb = (tid & 7) << 4;    // byte col 0..112 step 16

  const unsigned short* xrow[4];
  const unsigned short* wrow[4];
  int aoff[4];
#pragma unroll
  for (int p = 0; p < 4; ++p) {
    int r = p * 32 + trow;
    xrow[p] = X + (size_t)(m0 + r) * K + (tcb >> 1);
    int rn = n0 + r; if (rn > N - 1) rn = N - 1;     // clamp OOB N rows
    wrow[p] = W + (size_t)rn * K + (tcb >> 1);
    aoff[p] = r * 128 + (tcb ^ ((trow & 7) << 4));   // T2 XOR swizzle
  }
  const int rdswz = (l15 & 7) << 4;

  f32x4 acc[4][4];
  const f32x4 fz = {0.f, 0.f, 0.f, 0.f};
#pragma unroll
  for (int i = 0; i < 4; ++i)
#pragma unroll
    for (int j = 0; j < 4; ++j) acc[i][j] = fz;

  u16x8 stg[8];
#pragma unroll
  for (int p = 0; p < 4; ++p) {
    stg[p]     = *reinterpret_cast<const u16x8*>(xrow[p]);
    stg[4 + p] = *reinterpret_cast<const u16x8*>(wrow[p]);
  }

  for (int k0 = 0; k0 < K; k0 += 64) {
    __syncthreads();
#pragma unroll
    for (int p = 0; p < 4; ++p) {
      *reinterpret_cast<u16x8*>(reinterpret_cast<char*>(As) + aoff[p]) = stg[p];
      *reinterpret_cast<u16x8*>(reinterpret_cast<char*>(Bs) + aoff[p]) = stg[4 + p];
    }
    __syncthreads();
    if (k0 + 64 < K) {
#pragma unroll
      for (int p = 0; p < 4; ++p) {
        stg[p]     = *reinterpret_cast<const u16x8*>(xrow[p] + k0 + 64);
        stg[4 + p] = *reinterpret_cast<const u16x8*>(wrow[p] + k0 + 64);
      }
    }
#pragma unroll
    for (int kk = 0; kk < 2; ++kk) {
      const int kbyte = kk * 64 + g * 16;
      bf16x8 a[4], bb[4];
#pragma unroll
      for (int mi = 0; mi < 4; ++mi) {
        int ar = wr * 64 + mi * 16 + l15;
        a[mi] = *reinterpret_cast<const bf16x8*>(
            reinterpret_cast<const char*>(As) + ar * 128 + (kbyte ^ rdswz));
      }
#pragma unroll
      for (int ni = 0; ni < 4; ++ni) {
        int br = wc * 64 + ni * 16 + l15;
        bb[ni] = *reinterpret_cast<const bf16x8*>(
            reinterpret_cast<const char*>(Bs) + br * 128 + (kbyte ^ rdswz));
      }
#pragma unroll
      for (int mi = 0; mi < 4; ++mi)
#pragma unroll
        for (int ni = 0; ni < 4; ++ni)
          acc[mi][ni] = __builtin_amdgcn_mfma_f32_16x16x32_bf16(a[mi], bb[ni], acc[mi][ni], 0, 0, 0);
    }
  }
#pragma unroll
  for (int mi = 0; mi < 4; ++mi) {
#pragma unroll
    for (int ni = 0; ni < 4; ++ni) {
      int gn = n0 + wc * 64 + ni * 16 + l15;
      if (gn < N) {
        int gm = m0 + wr * 64 + mi * 16 + g * 4;
#pragma unroll
        for (int r = 0; r < 4; ++r) {
          size_t off2 = (size_t)(gm + r) * N + gn;
          float v = acc[mi][ni][r];
          if (EPI == 1) Cmat[off2] += v;
          else if (EPI == 2) Cmat[off2] = 30.f * tanhf(v * (1.f / 30.f));
          else Cmat[off2] = v;
        }
      }
    }
  }
}

// ---------------- flash attention (causal; ALiBi term is zero on causal region) ----------------
__global__ __launch_bounds__(256) void attn_kernel(
    const float* __restrict__ qkv, const unsigned short* __restrict__ vmix,
    unsigned short* __restrict__ ybf) {
  __shared__ unsigned short Kl[64 * 56];     // K tile, row pad 56
  __shared__ unsigned short Vt[48 * 72];     // V tile transposed [d][key], row pad 72
  __shared__ unsigned short Pl[4][16 * 72];  // per-wave P buffer [q][key]
  const int b = blockIdx.y / NH, h = blockIdx.y % NH;
  const int qb = blockIdx.x;
  const int tid = threadIdx.x, lane = tid & 63, wv = tid >> 6;
  const int l15 = lane & 15, g = lane >> 4;
  const int rb = b * TT;
  const int q0 = qb * 64 + wv * 16;
  const float scale = 0.14433756729740643f;  // 1/sqrt(48)

  // Q fragments (fp32 global -> bf16 regs), K-dim padded 48->64 with zeros
  bf16x8 qa[2];
  {
    const float* qp = qkv + (size_t)(rb + q0 + l15) * C3 + h * HD;
    union { bf16x8 v; unsigned short u[8]; } t0, t1;
#pragma unroll
    for (int j = 0; j < 8; ++j) t0.u[j] = f2bf(qp[8 * g + j]);
#pragma unroll
    for (int j = 0; j < 8; ++j) {
      int d = 32 + 8 * g + j;
      t1.u[j] = (d < HD) ? f2bf(qp[d]) : (unsigned short)0;
    }
    qa[0] = t0.v; qa[1] = t1.v;
  }

  float mrow[4], lrow[4];
  f32x4 o[3];
  const f32x4 fz = {0.f, 0.f, 0.f, 0.f};
#pragma unroll
  for (int r = 0; r < 4; ++r) { mrow[r] = -1e30f; lrow[r] = 0.f; }
  o[0] = fz; o[1] = fz; o[2] = fz;

  for (int kb = 0; kb <= qb; ++kb) {
    __syncthreads();
    // stage K tile (fp32 -> bf16)
#pragma unroll
    for (int jj = 0; jj < 3; ++jj) {
      int fi = tid + 256 * jj;                 // 0..767
      int r = fi / 12, dq = (fi % 12) * 4;
      const float4 v = *reinterpret_cast<const float4*>(
          qkv + (size_t)(rb + kb * 64 + r) * C3 + CC + h * HD + dq);
      ushort4 pk;
      pk.x = f2bf(v.x); pk.y = f2bf(v.y); pk.z = f2bf(v.z); pk.w = f2bf(v.w);
      *reinterpret_cast<ushort4*>(&Kl[r * 56 + dq]) = pk;
    }
    // stage V tile transposed (bf16 pass-through)
#pragma unroll
    for (int jj = 0; jj < 12; ++jj) {
      int e = tid + 256 * jj;                  // 0..3071
      int r = e / 48, d = e - r * 48;
      Vt[d * 72 + r] = vmix[(size_t)(rb + kb * 64 + r) * CC + h * HD + d];
    }
    __syncthreads();

    // S = Q K^T * scale
    f32x4 s[4];
    s[0] = fz; s[1] = fz; s[2] = fz; s[3] = fz;
#pragma unroll
    for (int c = 0; c < 2; ++c) {
#pragma unroll
      for (int t4 = 0; t4 < 4; ++t4) {
        bf16x8 kf;
        if (c == 1 && g >= 2) {
          u16x8 z = {0, 0, 0, 0, 0, 0, 0, 0};
          kf = __builtin_bit_cast(bf16x8, z);
        } else {
          kf = *reinterpret_cast<const bf16x8*>(&Kl[(t4 * 16 + l15) * 56 + c * 32 + 8 * g]);
        }
        s[t4] = __builtin_amdgcn_mfma_f32_16x16x32_bf16(qa[c], kf, s[t4], 0, 0, 0);
      }
    }
#pragma unroll
    for (int t4 = 0; t4 < 4; ++t4) s[t4] *= scale;
    if (kb == qb) {
#pragma unroll
      for (int t4 = 0; t4 < 4; ++t4) {
        int key = kb * 64 + t4 * 16 + l15;
#pragma unroll
        for (int r = 0; r < 4; ++r)
          if (key > q0 + g * 4 + r) s[t4][r] = -1e30f;
      }
    }
    // online softmax (rows live on lanes with same g; reduce across 16 lanes)
    float pv[4][4];
#pragma unroll
    for (int r = 0; r < 4; ++r) {
      float tm = fmaxf(fmaxf(s[0][r], s[1][r]), fmaxf(s[2][r], s[3][r]));
#pragma unroll
      for (int mm = 1; mm < 16; mm <<= 1) tm = fmaxf(tm, __shfl_xor(tm, mm, 64));
      float mnew = fmaxf(mrow[r], tm);
      float cf = __expf(mrow[r] - mnew);
      lrow[r] *= cf;
      o[0][r] *= cf; o[1][r] *= cf; o[2][r] *= cf;
      mrow[r] = mnew;
      float rs = 0.f;
#pragma unroll
      for (int t4 = 0; t4 < 4; ++t4) {
        float pe = __expf(s[t4][r] - mnew);
        pv[t4][r] = pe; rs += pe;
      }
#pragma unroll
      for (int mm = 1; mm < 16; mm <<= 1) rs += __shfl_xor(rs, mm, 64);
      lrow[r] += rs;
    }
    // P -> LDS (reshape C/D layout -> A layout), then PV
#pragma unroll
    for (int t4 = 0; t4 < 4; ++t4)
#pragma unroll
      for (int r = 0; r < 4; ++r)
        Pl[wv][(g * 4 + r) * 72 + t4 * 16 + l15] = f2bf(pv[t4][r]);
#pragma unroll
    for (int c = 0; c < 2; ++c) {
      bf16x8 pa = *reinterpret_cast<const bf16x8*>(&Pl[wv][l15 * 72 + c * 32 + 8 * g]);
#pragma unroll
      for (int dt = 0; dt < 3; ++dt) {
        bf16x8 vb = *reinterpret_cast<const bf16x8*>(&Vt[(dt * 16 + l15) * 72 + c * 32 + 8 * g]);
        o[dt] = __builtin_amdgcn_mfma_f32_16x16x32_bf16(pa, vb, o[dt], 0, 0, 0);
      }
    }
  }
#pragma unroll
  for (int r = 0; r < 4; ++r) {
    float inv = 1.f / lrow[r];
    int tr = q0 + g * 4 + r;
#pragma unroll
    for (int dt = 0; dt < 3; ++dt)
      ybf[(size_t)(rb + tr) * CC + h * HD + dt * 16 + l15] = f2bf(o[dt][r] * inv);
  }
}

// ---------------- launcher ----------------
extern "C" void kernel_launch(void* const* d_in, const int* in_sizes, int n_in,
                              void* d_out, int out_size, void* d_ws, size_t ws_size,
                              hipStream_t stream) {
  (void)in_sizes; (void)n_in; (void)out_size; (void)ws_size;
  const int*   idx  = (const int*)d_in[0];
  const float* wte  = (const float*)d_in[1];
  const float* Wqkv = (const float*)d_in[2];
  const float* Wo   = (const float*)d_in[3];
  const float* ln1w = (const float*)d_in[4];
  const float* ln1b = (const float*)d_in[5];
  const float* ln2w = (const float*)d_in[6];
  const float* ln2b = (const float*)d_in[7];
  const float* lam  = (const float*)d_in[8];
  const float* Wg   = (const float*)d_in[9];
  const float* Wu   = (const float*)d_in[10];
  const float* Wd   = (const float*)d_in[11];
  const float* lnfw = (const float*)d_in[12];
  const float* lnfb = (const float*)d_in[13];
  float* out = (float*)d_out;

  char* ws = (char*)d_ws;
  size_t off = 0;
  auto alloc = [&](size_t bytes) -> void* {
    void* p = ws + off;
    off = (off + bytes + 255) & ~(size_t)255;
    return p;
  };
  unsigned short* wqkv_b = (unsigned short*)alloc((size_t)NL * C3 * CC * 2);
  unsigned short* wo_b   = (unsigned short*)alloc((size_t)NL * CC * CC * 2);
  unsigned short* wg_b   = (unsigned short*)alloc((size_t)NL * C2 * CC * 2);
  unsigned short* wu_b   = (unsigned short*)alloc((size_t)NL * C2 * CC * 2);
  unsigned short* wd_b   = (unsigned short*)alloc((size_t)NL * CC * C2 * 2);
  unsigned short* wte_b  = (unsigned short*)alloc((size_t)VV * CC * 2);
  float* x     = (float*)alloc((size_t)BT * CC * 4);
  float* x0    = (float*)alloc((size_t)BT * CC * 4);
  unsigned short* hb = (unsigned short*)alloc((size_t)BT * CC * 2);
  float* qkvf  = (float*)alloc((size_t)BT * C3 * 4);
  float* v1f   = (float*)alloc((size_t)BT * CC * 4);
  unsigned short* vmixb = (unsigned short*)alloc((size_t)BT * CC * 2);
  unsigned short* yb    = (unsigned short*)alloc((size_t)BT * CC * 2);
  float* gf_   = (float*)alloc((size_t)BT * C2 * 4);
  float* uf_   = (float*)alloc((size_t)BT * C2 * 4);
  unsigned short* gub = (unsigned short*)alloc((size_t)BT * C2 * 2);

  auto cvt = [&](const float* in, unsigned short* o, size_t n) {
    cvt_kernel<<<dim3(2048), 256, 0, stream>>>(in, o, (int)(n / 4));
  };
  cvt(Wqkv, wqkv_b, (size_t)NL * C3 * CC);
  cvt(Wo,   wo_b,   (size_t)NL * CC * CC);
  cvt(Wg,   wg_b,   (size_t)NL * C2 * CC);
  cvt(Wu,   wu_b,   (size_t)NL * C2 * CC);
  cvt(Wd,   wd_b,   (size_t)NL * CC * C2);
  cvt(wte,  wte_b,  (size_t)VV * CC);

  embed_kernel<<<dim3(BT), 256, 0, stream>>>(idx, wte, x, x0, hb);

  auto gx = [](int N) { return (N + 127) / 128; };
  // v1 = raw-embed @ W_qkv[0][2C:3C]^T
  gemm_bt<0><<<dim3(gx(CC), 16), 256, 0, stream>>>(hb, wqkv_b + (size_t)2 * CC * CC, v1f, BT, CC, CC);

  for (int l = 0; l < NL; ++l) {
    ln_kernel<1><<<dim3(512), 256, 0, stream>>>(x, x0, lam + 2 * l, ln1w + l * CC, ln1b + l * CC, x, hb);
    gemm_bt<0><<<dim3(gx(C3), 16), 256, 0, stream>>>(hb, wqkv_b + (size_t)l * C3 * CC, qkvf, BT, C3, CC);
    vmix_kernel<<<dim3(1024), 256, 0, stream>>>(qkvf, v1f, vmixb);
    attn_kernel<<<dim3(16, 24), 256, 0, stream>>>(qkvf, vmixb, yb);
    gemm_bt<1><<<dim3(gx(CC), 16), 256, 0, stream>>>(yb, wo_b + (size_t)l * CC * CC, x, BT, CC, CC);
    ln_kernel<0><<<dim3(512), 256, 0, stream>>>(x, nullptr, nullptr, ln2w + l * CC, ln2b + l * CC, nullptr, hb);
    gemm_bt<0><<<dim3(gx(C2), 16), 256, 0, stream>>>(hb, wg_b + (size_t)l * C2 * CC, gf_, BT, C2, CC);
    gemm_bt<0><<<dim3(gx(C2), 16), 256, 0, stream>>>(hb, wu_b + (size_t)l * C2 * CC, uf_, BT, C2, CC);
    geglu_kernel<<<dim3(1024), 256, 0, stream>>>(gf_, uf_, gub);
    gemm_bt<1><<<dim3(gx(CC), 16), 256, 0, stream>>>(gub, wd_b + (size_t)l * CC * C2, x, BT, CC, C2);
  }

  ln_kernel<0><<<dim3(512), 256, 0, stream>>>(x, nullptr, nullptr, lnfw, lnfb, nullptr, hb);
  gemm_bt<2><<<dim3(gx(VV), 16), 256, 0, stream>>>(hb, wte_b, out, BT, VV, CC);
}

// Round 4
// 1358.745 us; speedup vs baseline: 1.1302x; 1.1302x over previous
//
#include <hip/hip_runtime.h>
#include <hip/hip_bf16.h>
#include <stdint.h>
#include <stddef.h>

#define NL 8
#define NH 12
#define CC 576
#define VV 16389
#define TT 1024
#define HD 48
#define BT 2048
#define C3 1728
#define C2 1152

typedef __attribute__((ext_vector_type(4))) float f32x4;
typedef __attribute__((ext_vector_type(8))) __bf16 bf16x8;
typedef __attribute__((ext_vector_type(8))) unsigned short u16x8;

static __device__ __forceinline__ unsigned short f2bf(float f) {
  __hip_bfloat16 h = __float2bfloat16(f);
  return __builtin_bit_cast(unsigned short, h);
}
static __device__ __forceinline__ float bf2f(unsigned short u) {
  __hip_bfloat16 h = __builtin_bit_cast(__hip_bfloat16, u);
  return __bfloat162float(h);
}
static __device__ __forceinline__ float gelu_tanh(float g) {
  float t = tanhf(0.7978845608028654f * (g + 0.044715f * g * g * g));
  return 0.5f * g * (1.f + t);
}

// ---------------- fp32 -> bf16 convert (weights) ----------------
__global__ void cvt_kernel(const float* __restrict__ in, unsigned short* __restrict__ out, int n4) {
  int i = blockIdx.x * blockDim.x + threadIdx.x;
  int stride = gridDim.x * blockDim.x;
  for (; i < n4; i += stride) {
    float4 v = reinterpret_cast<const float4*>(in)[i];
    ushort4 o;
    o.x = f2bf(v.x); o.y = f2bf(v.y); o.z = f2bf(v.z); o.w = f2bf(v.w);
    reinterpret_cast<ushort4*>(out)[i] = o;
  }
}

// gate/up row-interleave convert: out row 2j = Wg[j], row 2j+1 = Wu[j], per layer
__global__ void cvt_gu_kernel(const float* __restrict__ g, const float* __restrict__ u,
                              unsigned short* __restrict__ out, int n4) {
  int i = blockIdx.x * blockDim.x + threadIdx.x;
  int stride = gridDim.x * blockDim.x;
  const int per_l = C2 * (CC / 4);   // float4s per layer per matrix
  for (; i < n4; i += stride) {
    int l = i / per_l, rem = i - l * per_l;
    int j = rem / (CC / 4), c4 = rem - j * (CC / 4);
    float4 gv = reinterpret_cast<const float4*>(g)[i];
    float4 uv = reinterpret_cast<const float4*>(u)[i];
    ushort4 go, uo;
    go.x = f2bf(gv.x); go.y = f2bf(gv.y); go.z = f2bf(gv.z); go.w = f2bf(gv.w);
    uo.x = f2bf(uv.x); uo.y = f2bf(uv.y); uo.z = f2bf(uv.z); uo.w = f2bf(uv.w);
    size_t dst = ((size_t)l * 2 * C2 + 2 * j) * CC + c4 * 4;
    *reinterpret_cast<ushort4*>(out + dst) = go;
    *reinterpret_cast<ushort4*>(out + dst + CC) = uo;
  }
}

// ---------------- embedding gather ----------------
__global__ void embed_kernel(const int* __restrict__ idx, const float* __restrict__ wte,
                             float* __restrict__ x, float* __restrict__ x0,
                             unsigned short* __restrict__ xbf) {
  int t = blockIdx.x;
  int tok = idx[t];
  const float* src = wte + (size_t)tok * CC;
  size_t base = (size_t)t * CC;
  for (int c = threadIdx.x; c < CC; c += blockDim.x) {
    float v = src[c];
    x[base + c] = v;
    x0[base + c] = v;
    xbf[base + c] = f2bf(v);
  }
}

// ---------------- layernorm (+ optional lambda mix written back to x) ----------------
template<int MIX>
__global__ __launch_bounds__(256) void ln_kernel(
    const float* __restrict__ xin, const float* __restrict__ x0,
    const float* __restrict__ lam, const float* __restrict__ w,
    const float* __restrict__ b, float* __restrict__ xmix,
    unsigned short* __restrict__ hbf) {
  int row = blockIdx.x * 4 + (threadIdx.x >> 6);
  int lane = threadIdx.x & 63;
  size_t base = (size_t)row * CC;
  float lam0 = 1.f, lam1 = 0.f;
  if (MIX) { lam0 = lam[0]; lam1 = lam[1]; }
  float e[9];
  float s = 0.f;
#pragma unroll
  for (int j = 0; j < 9; ++j) {
    int c = lane + 64 * j;
    float v = xin[base + c];
    if (MIX) v = lam0 * v + lam1 * x0[base + c];
    e[j] = v; s += v;
  }
#pragma unroll
  for (int mm = 1; mm < 64; mm <<= 1) s += __shfl_xor(s, mm, 64);
  float mu = s * (1.f / 576.f);
  float var = 0.f;
#pragma unroll
  for (int j = 0; j < 9; ++j) { float d = e[j] - mu; var += d * d; }
#pragma unroll
  for (int mm = 1; mm < 64; mm <<= 1) var += __shfl_xor(var, mm, 64);
  float rstd = 1.f / sqrtf(var * (1.f / 576.f) + 1e-5f);
#pragma unroll
  for (int j = 0; j < 9; ++j) {
    int c = lane + 64 * j;
    if (MIX) xmix[base + c] = e[j];
    hbf[base + c] = f2bf((e[j] - mu) * rstd * w[c] + b[c]);
  }
}

// ---------------- bf16 MFMA GEMM: C[2048,N] (+)= X[2048,K] * W[N,K]^T ----------------
// M fixed 2048 (16 m-blocks of 128). 1D grid, m-fastest + bijective XCD swizzle.
// EPI: 0 fp32 store | 1 fp32 += (residual) | 2 30*tanh(v/30) fp32 | 3 bf16 store
//      4 qkv: cols<1152 -> bf16 qkb; cols>=1152 -> vmix = bf16(0.5v+0.5*v1b)
//      5 geglu on interleaved gate/up cols -> bf16, out stride N/2
template<int EPI, int BN>
__global__ __launch_bounds__(256) void gemm_bt(
    const unsigned short* __restrict__ X, const unsigned short* __restrict__ W,
    float* __restrict__ Cf, unsigned short* __restrict__ Cb,
    unsigned short* __restrict__ Cb2, const unsigned short* __restrict__ v1b,
    int N, int K) {
  constexpr int PB = BN / 32;        // B staging row-chunks
  constexpr int NI = BN / 32;        // per-wave 16-col frags in N
  __shared__ unsigned short As[128 * 64];
  __shared__ unsigned short Bs[BN * 64];
  const int tid = threadIdx.x;
  const int lane = tid & 63;
  const int wv = tid >> 6;
  const int wr = wv >> 1, wc = wv & 1;
  // XCD-aware swizzle: XCD x gets contiguous logical range; m-fastest inside
  const int nwg = gridDim.x;
  const int bid = blockIdx.x;
  const int swz = (bid & 7) * (nwg >> 3) + (bid >> 3);
  const int m0 = (swz & 15) * 128;
  const int n0 = (swz >> 4) * BN;
  const int l15 = lane & 15, g = lane >> 4;
  const int trow = tid >> 3;         // 0..31
  const int tcb = (tid & 7) << 4;    // byte col 0..112 step 16

  const unsigned short* xrow[4];
  const unsigned short* wrow[PB];
  int aoff[4], boff[PB];
#pragma unroll
  for (int p = 0; p < 4; ++p) {
    int r = p * 32 + trow;
    xrow[p] = X + (size_t)(m0 + r) * K + (tcb >> 1);
    aoff[p] = r * 128 + (tcb ^ ((trow & 7) << 4));   // T2 XOR swizzle
  }
#pragma unroll
  for (int p = 0; p < PB; ++p) {
    int r = p * 32 + trow;
    int rn = n0 + r; if (rn > N - 1) rn = N - 1;     // clamp OOB N rows
    wrow[p] = W + (size_t)rn * K + (tcb >> 1);
    boff[p] = r * 128 + (tcb ^ ((trow & 7) << 4));
  }
  const int rdswz = (l15 & 7) << 4;

  f32x4 acc[4][NI];
  const f32x4 fz = {0.f, 0.f, 0.f, 0.f};
#pragma unroll
  for (int i = 0; i < 4; ++i)
#pragma unroll
    for (int j = 0; j < NI; ++j) acc[i][j] = fz;

  u16x8 stg[4 + PB];
#pragma unroll
  for (int p = 0; p < 4; ++p) stg[p] = *reinterpret_cast<const u16x8*>(xrow[p]);
#pragma unroll
  for (int p = 0; p < PB; ++p) stg[4 + p] = *reinterpret_cast<const u16x8*>(wrow[p]);

  for (int k0 = 0; k0 < K; k0 += 64) {
    __syncthreads();
#pragma unroll
    for (int p = 0; p < 4; ++p)
      *reinterpret_cast<u16x8*>(reinterpret_cast<char*>(As) + aoff[p]) = stg[p];
#pragma unroll
    for (int p = 0; p < PB; ++p)
      *reinterpret_cast<u16x8*>(reinterpret_cast<char*>(Bs) + boff[p]) = stg[4 + p];
    __syncthreads();
    if (k0 + 64 < K) {
#pragma unroll
      for (int p = 0; p < 4; ++p)
        stg[p] = *reinterpret_cast<const u16x8*>(xrow[p] + k0 + 64);
#pragma unroll
      for (int p = 0; p < PB; ++p)
        stg[4 + p] = *reinterpret_cast<const u16x8*>(wrow[p] + k0 + 64);
    }
#pragma unroll
    for (int kk = 0; kk < 2; ++kk) {
      const int kbyte = kk * 64 + g * 16;
      bf16x8 a[4], bb[NI];
#pragma unroll
      for (int mi = 0; mi < 4; ++mi) {
        int ar = wr * 64 + mi * 16 + l15;
        a[mi] = *reinterpret_cast<const bf16x8*>(
            reinterpret_cast<const char*>(As) + ar * 128 + (kbyte ^ rdswz));
      }
#pragma unroll
      for (int ni = 0; ni < NI; ++ni) {
        int br = wc * (BN / 2) + ni * 16 + l15;
        bb[ni] = *reinterpret_cast<const bf16x8*>(
            reinterpret_cast<const char*>(Bs) + br * 128 + (kbyte ^ rdswz));
      }
#pragma unroll
      for (int mi = 0; mi < 4; ++mi)
#pragma unroll
        for (int ni = 0; ni < NI; ++ni)
          acc[mi][ni] = __builtin_amdgcn_mfma_f32_16x16x32_bf16(a[mi], bb[ni], acc[mi][ni], 0, 0, 0);
    }
  }
#pragma unroll
  for (int mi = 0; mi < 4; ++mi) {
#pragma unroll
    for (int ni = 0; ni < NI; ++ni) {
      int gn = n0 + wc * (BN / 2) + ni * 16 + l15;
      int gm = m0 + wr * 64 + mi * 16 + g * 4;
#pragma unroll
      for (int r = 0; r < 4; ++r) {
        float v = acc[mi][ni][r];
        size_t row = (size_t)(gm + r);
        if (EPI == 5) {
          // interleaved gate/up: even col = gate, odd = up
          float partner = __shfl_xor(v, 1, 64);
          if ((l15 & 1) == 0 && gn < N)
            Cb[row * (N / 2) + (gn >> 1)] = f2bf(gelu_tanh(v) * partner);
        } else if (gn < N) {
          if (EPI == 0) Cf[row * N + gn] = v;
          else if (EPI == 1) Cf[row * N + gn] += v;
          else if (EPI == 2) Cf[row * N + gn] = 30.f * tanhf(v * (1.f / 30.f));
          else if (EPI == 3) Cb[row * N + gn] = f2bf(v);
          else if (EPI == 4) {
            if (gn < C2) Cb[row * C2 + gn] = f2bf(v);                       // q,k
            else Cb2[row * CC + (gn - C2)] = f2bf(0.5f * v + 0.5f * bf2f(v1b[row * CC + (gn - C2)]));
          }
        }
      }
    }
  }
}

// ---------------- flash attention (causal; ALiBi dead on causal region) ----------------
// qkb: bf16 [2048][1152] (q cols 0..575, k cols 576..1151); vmix: bf16 [2048][576]
__global__ __launch_bounds__(256) void attn_kernel(
    const unsigned short* __restrict__ qkb, const unsigned short* __restrict__ vmix,
    unsigned short* __restrict__ ybf) {
  __shared__ unsigned short Kl[64 * 56];     // K tile, row pad 56
  __shared__ unsigned short Vt[48 * 72];     // V tile transposed [d][key], row pad 72
  __shared__ unsigned short Pl[4][16 * 72];  // per-wave P buffer [q][key]
  const int bid = blockIdx.x;                // 384 = 8*48
  const int swz = (bid & 7) * 48 + (bid >> 3);
  const int qb = swz & 15, bh = swz >> 4;
  const int b = bh / NH, h = bh % NH;
  const int tid = threadIdx.x, lane = tid & 63, wv = tid >> 6;
  const int l15 = lane & 15, g = lane >> 4;
  const int rb = b * TT;
  const int q0 = qb * 64 + wv * 16;
  const float scale = 0.14433756729740643f;  // 1/sqrt(48)

  // Q fragments straight from bf16, K-dim padded 48->64 with zeros
  bf16x8 qa[2];
  {
    const unsigned short* qp = qkb + (size_t)(rb + q0 + l15) * C2 + h * HD;
    qa[0] = *reinterpret_cast<const bf16x8*>(qp + 8 * g);
    if (g < 2) qa[1] = *reinterpret_cast<const bf16x8*>(qp + 32 + 8 * g);
    else { u16x8 z = {0,0,0,0,0,0,0,0}; qa[1] = __builtin_bit_cast(bf16x8, z); }
  }

  float mrow[4], lrow[4];
  f32x4 o[3];
  const f32x4 fz = {0.f, 0.f, 0.f, 0.f};
#pragma unroll
  for (int r = 0; r < 4; ++r) { mrow[r] = -1e30f; lrow[r] = 0.f; }
  o[0] = fz; o[1] = fz; o[2] = fz;

  for (int kb = 0; kb <= qb; ++kb) {
    __syncthreads();
    // stage K tile (bf16 copy)
#pragma unroll
    for (int jj = 0; jj < 3; ++jj) {
      int fi = tid + 256 * jj;                 // 0..767
      int r = fi / 12, dq = (fi % 12) * 4;
      *reinterpret_cast<ushort4*>(&Kl[r * 56 + dq]) =
          *reinterpret_cast<const ushort4*>(qkb + (size_t)(rb + kb * 64 + r) * C2 + CC + h * HD + dq);
    }
    // stage V tile transposed
#pragma unroll
    for (int jj = 0; jj < 12; ++jj) {
      int e = tid + 256 * jj;                  // 0..3071
      int r = e / 48, d = e - r * 48;
      Vt[d * 72 + r] = vmix[(size_t)(rb + kb * 64 + r) * CC + h * HD + d];
    }
    __syncthreads();

    // S = Q K^T * scale
    f32x4 s[4];
    s[0] = fz; s[1] = fz; s[2] = fz; s[3] = fz;
#pragma unroll
    for (int c = 0; c < 2; ++c) {
#pragma unroll
      for (int t4 = 0; t4 < 4; ++t4) {
        bf16x8 kf;
        if (c == 1 && g >= 2) {
          u16x8 z = {0,0,0,0,0,0,0,0};
          kf = __builtin_bit_cast(bf16x8, z);
        } else {
          kf = *reinterpret_cast<const bf16x8*>(&Kl[(t4 * 16 + l15) * 56 + c * 32 + 8 * g]);
        }
        s[t4] = __builtin_amdgcn_mfma_f32_16x16x32_bf16(qa[c], kf, s[t4], 0, 0, 0);
      }
    }
#pragma unroll
    for (int t4 = 0; t4 < 4; ++t4) s[t4] *= scale;
    if (kb == qb) {
#pragma unroll
      for (int t4 = 0; t4 < 4; ++t4) {
        int key = kb * 64 + t4 * 16 + l15;
#pragma unroll
        for (int r = 0; r < 4; ++r)
          if (key > q0 + g * 4 + r) s[t4][r] = -1e30f;
      }
    }
    // online softmax (row lives across 16 lanes sharing g)
    float pv[4][4];
#pragma unroll
    for (int r = 0; r < 4; ++r) {
      float tm = fmaxf(fmaxf(s[0][r], s[1][r]), fmaxf(s[2][r], s[3][r]));
#pragma unroll
      for (int mm = 1; mm < 16; mm <<= 1) tm = fmaxf(tm, __shfl_xor(tm, mm, 64));
      float mnew = fmaxf(mrow[r], tm);
      float cf = __expf(mrow[r] - mnew);
      lrow[r] *= cf;
      o[0][r] *= cf; o[1][r] *= cf; o[2][r] *= cf;
      mrow[r] = mnew;
      float rs = 0.f;
#pragma unroll
      for (int t4 = 0; t4 < 4; ++t4) {
        float pe = __expf(s[t4][r] - mnew);
        pv[t4][r] = pe; rs += pe;
      }
#pragma unroll
      for (int mm = 1; mm < 16; mm <<= 1) rs += __shfl_xor(rs, mm, 64);
      lrow[r] += rs;
    }
    // P -> LDS (C/D layout -> A layout), then PV
#pragma unroll
    for (int t4 = 0; t4 < 4; ++t4)
#pragma unroll
      for (int r = 0; r < 4; ++r)
        Pl[wv][(g * 4 + r) * 72 + t4 * 16 + l15] = f2bf(pv[t4][r]);
#pragma unroll
    for (int c = 0; c < 2; ++c) {
      bf16x8 pa = *reinterpret_cast<const bf16x8*>(&Pl[wv][l15 * 72 + c * 32 + 8 * g]);
#pragma unroll
      for (int dt = 0; dt < 3; ++dt) {
        bf16x8 vb = *reinterpret_cast<const bf16x8*>(&Vt[(dt * 16 + l15) * 72 + c * 32 + 8 * g]);
        o[dt] = __builtin_amdgcn_mfma_f32_16x16x32_bf16(pa, vb, o[dt], 0, 0, 0);
      }
    }
  }
#pragma unroll
  for (int r = 0; r < 4; ++r) {
    float inv = 1.f / lrow[r];
    int tr = q0 + g * 4 + r;
#pragma unroll
    for (int dt = 0; dt < 3; ++dt)
      ybf[(size_t)(rb + tr) * CC + h * HD + dt * 16 + l15] = f2bf(o[dt][r] * inv);
  }
}

// ---------------- launcher ----------------
extern "C" void kernel_launch(void* const* d_in, const int* in_sizes, int n_in,
                              void* d_out, int out_size, void* d_ws, size_t ws_size,
                              hipStream_t stream) {
  (void)in_sizes; (void)n_in; (void)out_size; (void)ws_size;
  const int*   idx  = (const int*)d_in[0];
  const float* wte  = (const float*)d_in[1];
  const float* Wqkv = (const float*)d_in[2];
  const float* Wo   = (const float*)d_in[3];
  const float* ln1w = (const float*)d_in[4];
  const float* ln1b = (const float*)d_in[5];
  const float* ln2w = (const float*)d_in[6];
  const float* ln2b = (const float*)d_in[7];
  const float* lam  = (const float*)d_in[8];
  const float* Wg   = (const float*)d_in[9];
  const float* Wu   = (const float*)d_in[10];
  const float* Wd   = (const float*)d_in[11];
  const float* lnfw = (const float*)d_in[12];
  const float* lnfb = (const float*)d_in[13];
  float* out = (float*)d_out;

  char* ws = (char*)d_ws;
  size_t off = 0;
  auto alloc = [&](size_t bytes) -> void* {
    void* p = ws + off;
    off = (off + bytes + 255) & ~(size_t)255;
    return p;
  };
  unsigned short* wqkv_b = (unsigned short*)alloc((size_t)NL * C3 * CC * 2);
  unsigned short* wo_b   = (unsigned short*)alloc((size_t)NL * CC * CC * 2);
  unsigned short* wgu_b  = (unsigned short*)alloc((size_t)NL * 2 * C2 * CC * 2);
  unsigned short* wd_b   = (unsigned short*)alloc((size_t)NL * CC * C2 * 2);
  unsigned short* wte_b  = (unsigned short*)alloc((size_t)VV * CC * 2);
  float* x     = (float*)alloc((size_t)BT * CC * 4);
  float* x0    = (float*)alloc((size_t)BT * CC * 4);
  unsigned short* hb    = (unsigned short*)alloc((size_t)BT * CC * 2);
  unsigned short* qkb   = (unsigned short*)alloc((size_t)BT * C2 * 2);
  unsigned short* v1b   = (unsigned short*)alloc((size_t)BT * CC * 2);
  unsigned short* vmixb = (unsigned short*)alloc((size_t)BT * CC * 2);
  unsigned short* yb    = (unsigned short*)alloc((size_t)BT * CC * 2);
  unsigned short* gub   = (unsigned short*)alloc((size_t)BT * C2 * 2);

  auto cvt = [&](const float* in, unsigned short* o, size_t n) {
    cvt_kernel<<<dim3(2048), 256, 0, stream>>>(in, o, (int)(n / 4));
  };
  cvt(Wqkv, wqkv_b, (size_t)NL * C3 * CC);
  cvt(Wo,   wo_b,   (size_t)NL * CC * CC);
  cvt(Wd,   wd_b,   (size_t)NL * CC * C2);
  cvt(wte,  wte_b,  (size_t)VV * CC);
  cvt_gu_kernel<<<dim3(2048), 256, 0, stream>>>(Wg, Wu, wgu_b, NL * C2 * (CC / 4));

  embed_kernel<<<dim3(BT), 256, 0, stream>>>(idx, wte, x, x0, hb);

  auto nb = [](int N, int BN) { return (N + BN - 1) / BN; };
  // v1 = raw-embed @ W_qkv[0] v-chunk^T  -> bf16
  gemm_bt<3, 64><<<dim3(16 * nb(CC, 64)), 256, 0, stream>>>(
      hb, wqkv_b + (size_t)C2 * CC, nullptr, v1b, nullptr, nullptr, CC, CC);

  for (int l = 0; l < NL; ++l) {
    ln_kernel<1><<<dim3(512), 256, 0, stream>>>(x, x0, lam + 2 * l, ln1w + l * CC, ln1b + l * CC, x, hb);
    gemm_bt<4, 128><<<dim3(16 * nb(C3, 128)), 256, 0, stream>>>(
        hb, wqkv_b + (size_t)l * C3 * CC, nullptr, qkb, vmixb, v1b, C3, CC);
    attn_kernel<<<dim3(16 * 24), 256, 0, stream>>>(qkb, vmixb, yb);
    gemm_bt<1, 64><<<dim3(16 * nb(CC, 64)), 256, 0, stream>>>(
        yb, wo_b + (size_t)l * CC * CC, x, nullptr, nullptr, nullptr, CC, CC);
    ln_kernel<0><<<dim3(512), 256, 0, stream>>>(x, nullptr, nullptr, ln2w + l * CC, ln2b + l * CC, nullptr, hb);
    gemm_bt<5, 128><<<dim3(16 * nb(2 * C2, 128)), 256, 0, stream>>>(
        hb, wgu_b + (size_t)l * 2 * C2 * CC, nullptr, gub, nullptr, nullptr, 2 * C2, CC);
    gemm_bt<1, 64><<<dim3(16 * nb(CC, 64)), 256, 0, stream>>>(
        gub, wd_b + (size_t)l * CC * C2, x, nullptr, nullptr, nullptr, CC, C2);
  }

  ln_kernel<0><<<dim3(512), 256, 0, stream>>>(x, nullptr, nullptr, lnfw, lnfb, nullptr, hb);
  gemm_bt<2, 128><<<dim3(16 * nb(VV, 128)), 256, 0, stream>>>(
      hb, wte_b, out, nullptr, nullptr, nullptr, VV, CC);
}